// Round 12
// baseline (196.059 us; speedup 1.0000x reference)
//
#include <hip/hip_runtime.h>
#include <hip/hip_bf16.h>
#include <stdint.h>

// Fixed problem shape: B=2, S=2048, E=1024, H=16, Dh=64, fp32 in/out.
#define S_LEN 2048
#define E_DIM 1024
#define NHEAD 16
#define DHEAD 64
#define BATCH 2

typedef short bf16x8 __attribute__((ext_vector_type(8)));  // 8 bf16 in 4 VGPRs
typedef float f32x4 __attribute__((ext_vector_type(4)));
typedef float f32x16 __attribute__((ext_vector_type(16)));

__device__ __forceinline__ ushort f2bf(float f) {
    uint32_t u = __builtin_bit_cast(uint32_t, f);
    u += 0x7fffu + ((u >> 16) & 1u);       // round-to-nearest-even
    return (ushort)(u >> 16);
}
__device__ __forceinline__ uint32_t cvtpk(float lo, float hi) {
    // single-instruction RNE pack: lo -> [15:0], hi -> [31:16]
    uint32_t r;
    asm("v_cvt_pk_bf16_f32 %0, %1, %2" : "=v"(r) : "v"(lo), "v"(hi));
    return r;
}
__device__ __forceinline__ f32x16 zero16() {
    f32x16 v;
    #pragma unroll
    for (int i = 0; i < 16; ++i) v[i] = 0.f;
    return v;
}
// async global->LDS DMA, 16B per lane; LDS dst is wave-uniform base + lane*16B
__device__ __forceinline__ void gload16(const void* g, void* l) {
    __builtin_amdgcn_global_load_lds(
        (const __attribute__((address_space(1))) uint32_t*)g,
        (__attribute__((address_space(3))) uint32_t*)l, 16, 0, 0);
}

// ---------------------------------------------------------------------------
// fp32 -> bf16 convert: blockIdx.y selects {x, Wq, Wk, Wv}
// ---------------------------------------------------------------------------
__global__ __launch_bounds__(256) void convert_kernel(
    const float* __restrict__ x, const float* __restrict__ wq,
    const float* __restrict__ wk, const float* __restrict__ wv,
    ushort* __restrict__ xb, ushort* __restrict__ wqb,
    ushort* __restrict__ wkb, ushort* __restrict__ wvb)
{
    const int a = blockIdx.y;
    const float* src = (a == 0) ? x : (a == 1) ? wq : (a == 2) ? wk : wv;
    ushort* dst      = (a == 0) ? xb : (a == 1) ? wqb : (a == 2) ? wkb : wvb;
    const int n4 = (a == 0) ? (BATCH * S_LEN * E_DIM / 4) : (E_DIM * E_DIM / 4);
    const int idx = blockIdx.x * 256 + threadIdx.x;
    if (idx < n4) {
        float4 v = reinterpret_cast<const float4*>(src)[idx];
        ushort4 o;
        o.x = f2bf(v.x); o.y = f2bf(v.y); o.z = f2bf(v.z); o.w = f2bf(v.w);
        reinterpret_cast<ushort4*>(dst)[idx] = o;
    }
}

// ---------------------------------------------------------------------------
// MFMA GEMM: gload16 staging with PRE-SWIZZLED global source (G21): LDS stays
// linear [128][64]; lane fetches global 16B slot (l&7)^(row&7) so that the
// swizzled ds_read (slot ^ row&7) is bank-conflict-free (2-way max).
// BK=64 (16 K-iters, half the barriers of BK=32).
// z=0: q = x·Wq^T -> qb [B,H,S,Dh]; z=1: k -> kb; z=2: v^T = Wv·x^T -> vtb.
// ---------------------------------------------------------------------------
__global__ __launch_bounds__(256) void qkv_mfma_kernel(
    const ushort* __restrict__ xb, const ushort* __restrict__ wqb,
    const ushort* __restrict__ wkb, const ushort* __restrict__ wvb,
    const float* __restrict__ bq, const float* __restrict__ bk,
    const float* __restrict__ bv,
    ushort* __restrict__ qb, ushort* __restrict__ kb, ushort* __restrict__ vtb)
{
    const int z = blockIdx.z;
    const ushort* Ag; const ushort* Bg; const float* bias;
    int m0, n0;
    if (z == 2) { Ag = wvb; Bg = xb;                 bias = bv;
                  m0 = blockIdx.y * 128; n0 = blockIdx.x * 128; }
    else        { Ag = xb;  Bg = (z == 0) ? wqb : wkb; bias = (z == 0) ? bq : bk;
                  m0 = blockIdx.x * 128; n0 = blockIdx.y * 128; }

    __shared__ ushort As[128 * 64];   // linear rows of 128B (8 slots x 16B)
    __shared__ ushort Bs[128 * 64];

    const int tid  = threadIdx.x;
    const int lane = tid & 63;
    const int wid  = tid >> 6;
    const int wr   = wid >> 1, wc = wid & 1;

    f32x4 acc[4][4];
    #pragma unroll
    for (int i = 0; i < 4; ++i)
        #pragma unroll
        for (int j = 0; j < 4; ++j) acc[i][j] = (f32x4){0.f, 0.f, 0.f, 0.f};

    const int crow  = lane >> 3;        // 0..7 row within an 8-row chunk
    const int cslot = lane & 7;         // 16B slot within 128B row
    const int lr    = lane & 15;
    const int lq    = lane >> 4;        // 0..3

    for (int k0 = 0; k0 < E_DIM; k0 += 64) {
        // wave w stages rows [w*32, w*32+32) of A and B: 4 chunks of 8 rows
        #pragma unroll
        for (int j = 0; j < 4; ++j) {
            const int rbase = wid * 32 + j * 8;
            const int srow  = rbase + crow;
            const int sslot = cslot ^ (srow & 7);   // pre-swizzled source
            gload16(&Ag[(size_t)(m0 + srow) * E_DIM + k0 + sslot * 8],
                    &As[rbase * 64]);
            gload16(&Bg[(size_t)(n0 + srow) * E_DIM + k0 + sslot * 8],
                    &Bs[rbase * 64]);
        }
        __syncthreads();   // drains vmcnt (gload_lds)

        #pragma unroll
        for (int ks = 0; ks < 2; ++ks) {
            bf16x8 af[4], bf[4];
            #pragma unroll
            for (int mi = 0; mi < 4; ++mi) {
                const int row  = wr * 64 + mi * 16 + lr;
                const int slot = (ks * 4 + lq) ^ (row & 7);
                af[mi] = *reinterpret_cast<const bf16x8*>(
                    &As[row * 64 + slot * 8]);
            }
            #pragma unroll
            for (int ni = 0; ni < 4; ++ni) {
                const int row  = wc * 64 + ni * 16 + lr;
                const int slot = (ks * 4 + lq) ^ (row & 7);
                bf[ni] = *reinterpret_cast<const bf16x8*>(
                    &Bs[row * 64 + slot * 8]);
            }
            #pragma unroll
            for (int mi = 0; mi < 4; ++mi)
                #pragma unroll
                for (int ni = 0; ni < 4; ++ni)
                    acc[mi][ni] = __builtin_amdgcn_mfma_f32_16x16x32_bf16(
                        af[mi], bf[ni], acc[mi][ni], 0, 0, 0);
        }
        __syncthreads();
    }

    const int rq = lane >> 4;
    #pragma unroll
    for (int mi = 0; mi < 4; ++mi) {
        #pragma unroll
        for (int ni = 0; ni < 4; ++ni) {
            #pragma unroll
            for (int r = 0; r < 4; ++r) {
                const int i = m0 + wr * 64 + mi * 16 + rq * 4 + r;
                const int j = n0 + wc * 64 + ni * 16 + lr;
                float val = acc[mi][ni][r];
                if (z == 2) {
                    val += bias[i];
                    const int h = i >> 6, d = i & 63;
                    const int b = j >> 11, s = j & (S_LEN - 1);
                    vtb[(((size_t)(b * NHEAD + h)) * DHEAD + d) * S_LEN + s] = f2bf(val);
                } else {
                    val += bias[j];
                    const int h = j >> 6, d = j & 63;
                    const int b = i >> 11, s = i & (S_LEN - 1);
                    ushort* o = (z == 0) ? qb : kb;
                    o[(((size_t)(b * NHEAD + h)) * S_LEN + s) * DHEAD + d] = f2bf(val);
                }
            }
        }
    }
}

// ---------------------------------------------------------------------------
// Attention v4: 8 waves x 32 q = QBLK 256 (halved K/V traffic+staging/q-row),
// __expf ln-domain softmax (native v_exp path, not OCML exp2), tree-reduced
// max/lsum (depth 5 vs serial 31), double-buffered K/V with T14 async-stage,
// cvt_pk P packing, in-register P via half-swap shuffles, swapped QK^T / PV.
// grid = 256 blocks x 512 threads; LDS 64 KB.
// ---------------------------------------------------------------------------
__global__ __launch_bounds__(512) void attn_mfma32_kernel(
    const ushort* __restrict__ qb, const ushort* __restrict__ kb,
    const ushort* __restrict__ vtb, float* __restrict__ out)
{
    // XCD-aware bijective swizzle: 256 blocks, 8 q-blocks per (b,h) share L2
    const int bid = blockIdx.x;
    const int swzb = (bid & 7) * 32 + (bid >> 3);
    const int bh = swzb >> 3;            // 0..31
    const int q0 = (swzb & 7) * 256;
    const int b = bh >> 4, h = bh & 15;
    const ushort* Q  = qb  + (size_t)bh * S_LEN * DHEAD;
    const ushort* K  = kb  + (size_t)bh * S_LEN * DHEAD;
    const ushort* Vt = vtb + (size_t)bh * DHEAD * S_LEN;   // [Dh][S]

    __shared__ ushort Qs[256 * 64];      // 32 KB
    __shared__ ushort KV[2][2 * 64 * 64];// 2 x (Ks 8KB | Vs 8KB) = 32 KB

    const int tid  = threadIdx.x;        // 0..511
    const int lane = tid & 63;
    const int wid  = tid >> 6;           // 0..7
    const int hi   = lane >> 5;          // k-half selector in A/B frags
    const int l31  = lane & 31;
    const int swzr = (lane & 7) << 3;    // frag-read swizzle (ushort units)
    const float SC = 0.125f;             // 1/sqrt(64); ln-domain softmax

    const int stslot = (tid & 7) * 8;    // staging: 8 lanes x 16B per row
    const int strow  = tid >> 3;         // 0..63

    // ---- stage Q [256][64] swizzled ----
    #pragma unroll
    for (int p = 0; p < 4; ++p) {
        const int row = strow + p * 64;
        bf16x8 v = *reinterpret_cast<const bf16x8*>(
            &Q[(size_t)(q0 + row) * DHEAD + stslot]);
        *reinterpret_cast<bf16x8*>(
            &Qs[row * 64 + (stslot ^ ((row & 7) << 3))]) = v;
    }

    // issue tile-0 K/V loads (one 16B chunk per thread)
    bf16x8 kreg, vreg;
    kreg = *reinterpret_cast<const bf16x8*>(&K[(size_t)strow * DHEAD + stslot]);
    vreg = *reinterpret_cast<const bf16x8*>(&Vt[(size_t)strow * S_LEN + stslot]);
    __syncthreads();                     // Qs visible

    bf16x8 qf[4];
    {
        const int qrow = wid * 32 + l31;
        #pragma unroll
        for (int st = 0; st < 4; ++st)
            qf[st] = *reinterpret_cast<const bf16x8*>(
                &Qs[qrow * 64 + ((st * 16 + hi * 8) ^ ((qrow & 7) << 3))]);
    }

    // write tile 0 into buf 0
    {
        const int sw = strow * 64 + (stslot ^ ((strow & 7) << 3));
        *reinterpret_cast<bf16x8*>(&KV[0][sw])           = kreg;
        *reinterpret_cast<bf16x8*>(&KV[0][64 * 64 + sw]) = vreg;
    }
    __syncthreads();

    float m_run = -1e30f, l_run = 0.f;
    f32x16 oacc[2] = {zero16(), zero16()};
    int cur = 0;

    for (int t0 = 0; t0 < S_LEN; t0 += 64) {
        const bool more = (t0 + 64 < S_LEN);
        if (more) {                      // T14: issue next-tile loads EARLY
            const int tn = t0 + 64;
            kreg = *reinterpret_cast<const bf16x8*>(
                &K[(size_t)(tn + strow) * DHEAD + stslot]);
            vreg = *reinterpret_cast<const bf16x8*>(
                &Vt[(size_t)strow * S_LEN + tn + stslot]);
        }

        const ushort* Ks = &KV[cur][0];
        const ushort* Vs = &KV[cur][64 * 64];

        // ---- swapped QK^T: C[row=kv][col=q] ----
        f32x16 sacc[2] = {zero16(), zero16()};
        #pragma unroll
        for (int t = 0; t < 2; ++t) {
            const int kbase = (t * 32 + l31) * 64;
            #pragma unroll
            for (int st = 0; st < 4; ++st) {
                bf16x8 kf = *reinterpret_cast<const bf16x8*>(
                    &Ks[kbase + ((st * 16 + hi * 8) ^ swzr)]);
                sacc[t] = __builtin_amdgcn_mfma_f32_32x32x16_bf16(
                    kf, qf[st], sacc[t], 0, 0, 0);
            }
        }

        // ---- tree row-max (depth 5, q = lane&31 lane-local) ----
        float m8[8];
        #pragma unroll
        for (int i = 0; i < 8; ++i)
            m8[i] = fmaxf(fmaxf(sacc[0][i], sacc[0][i + 8]),
                          fmaxf(sacc[1][i], sacc[1][i + 8]));
        float mx = fmaxf(fmaxf(fmaxf(m8[0], m8[4]), fmaxf(m8[1], m8[5])),
                         fmaxf(fmaxf(m8[2], m8[6]), fmaxf(m8[3], m8[7])));
        mx = fmaxf(mx, __shfl_xor(mx, 32));
        const float mt = mx * SC;

        if (__any(mt > m_run + 8.0f)) {          // defer-max (T13)
            const float mn = fmaxf(m_run, mt);
            const float al = __expf(m_run - mn);
            m_run = mn;
            l_run *= al;
            #pragma unroll
            for (int r = 0; r < 16; ++r) { oacc[0][r] *= al; oacc[1][r] *= al; }
        }

        // ---- p = exp(s*SC - m); cvt_pk pairs; swap-across-hi -> P frags ----
        float csum[4];
        uint32_t w[4][4];                        // [chunk][word] PV B-frag words
        #pragma unroll
        for (int t = 0; t < 2; ++t) {
            #pragma unroll
            for (int half = 0; half < 2; ++half) {
                float p[8];
                #pragma unroll
                for (int j = 0; j < 8; ++j)
                    p[j] = __expf(fmaf(sacc[t][half * 8 + j], SC, -m_run));
                const int c = t * 2 + half;
                csum[c] = (p[0] + p[1]) + (p[2] + p[3]) +
                          ((p[4] + p[5]) + (p[6] + p[7]));
                const uint32_t a0 = cvtpk(p[0], p[1]);
                const uint32_t a1 = cvtpk(p[2], p[3]);
                const uint32_t b0 = cvtpk(p[4], p[5]);
                const uint32_t b1 = cvtpk(p[6], p[7]);
                const uint32_t xs0 = __shfl_xor(a0, 32);
                const uint32_t ys0 = __shfl_xor(b0, 32);
                const uint32_t xs1 = __shfl_xor(a1, 32);
                const uint32_t ys1 = __shfl_xor(b1, 32);
                w[c][0] = hi ? ys0 : a0;
                w[c][2] = hi ? b0  : xs0;
                w[c][1] = hi ? ys1 : a1;
                w[c][3] = hi ? b1  : xs1;
            }
        }
        float lsum = (csum[0] + csum[1]) + (csum[2] + csum[3]);
        lsum += __shfl_xor(lsum, 32);
        l_run += lsum;

        // ---- PV (swapped): oacc[dblk] += mfma(Vt_frag, P_frag) -> C[d][q] ----
        #pragma unroll
        for (int c = 0; c < 4; ++c) {
            union { uint32_t u[4]; bf16x8 v; } pf;
            pf.u[0] = w[c][0]; pf.u[1] = w[c][1];
            pf.u[2] = w[c][2]; pf.u[3] = w[c][3];
            #pragma unroll
            for (int dblk = 0; dblk < 2; ++dblk) {
                const int vrow = dblk * 32 + l31;
                bf16x8 vf = *reinterpret_cast<const bf16x8*>(
                    &Vs[vrow * 64 + ((c * 16 + hi * 8) ^ swzr)]);
                oacc[dblk] = __builtin_amdgcn_mfma_f32_32x32x16_bf16(
                    vf, pf.v, oacc[dblk], 0, 0, 0);
            }
        }

        if (more) {
            __syncthreads();             // all waves done compute(t)
            const int sw = strow * 64 + (stslot ^ ((strow & 7) << 3));
            *reinterpret_cast<bf16x8*>(&KV[cur ^ 1][sw])           = kreg;
            *reinterpret_cast<bf16x8*>(&KV[cur ^ 1][64 * 64 + sw]) = vreg;
            __syncthreads();             // writes visible
            cur ^= 1;
        }
    }

    // ---- epilogue: out[b][q][h*64+d], d = (r&3)+8*(r>>2)+4*hi+32*dblk ----
    const float inv = 1.f / l_run;
    const int qg = q0 + wid * 32 + l31;
    float* obase = &out[((size_t)(b * S_LEN + qg)) * E_DIM + h * DHEAD];
    #pragma unroll
    for (int dblk = 0; dblk < 2; ++dblk) {
        #pragma unroll
        for (int g = 0; g < 4; ++g) {
            float4 f;
            f.x = oacc[dblk][g * 4 + 0] * inv;
            f.y = oacc[dblk][g * 4 + 1] * inv;
            f.z = oacc[dblk][g * 4 + 2] * inv;
            f.w = oacc[dblk][g * 4 + 3] * inv;
            *reinterpret_cast<float4*>(&obase[dblk * 32 + g * 8 + hi * 4]) = f;
        }
    }
}

// ---------------------------------------------------------------------------
extern "C" void kernel_launch(void* const* d_in, const int* in_sizes, int n_in,
                              void* d_out, int out_size, void* d_ws, size_t ws_size,
                              hipStream_t stream) {
    const float* x  = (const float*)d_in[0];
    const float* Wq = (const float*)d_in[1];
    const float* bq = (const float*)d_in[2];
    const float* Wk = (const float*)d_in[3];
    const float* bk = (const float*)d_in[4];
    const float* Wv = (const float*)d_in[5];
    const float* bv = (const float*)d_in[6];
    float* out = (float*)d_out;

    const size_t XN = (size_t)BATCH * S_LEN * E_DIM;   // 4M elems
    const size_t WN = (size_t)E_DIM * E_DIM;           // 1M elems
    ushort* xb  = (ushort*)d_ws;
    ushort* wqb = xb  + XN;
    ushort* wkb = wqb + WN;
    ushort* wvb = wkb + WN;
    ushort* qbb = wvb + WN;
    ushort* kbb = qbb + XN;
    ushort* vtb = kbb + XN;   // total ~38 MB

    convert_kernel<<<dim3(4096, 4), 256, 0, stream>>>(
        x, Wq, Wk, Wv, xb, wqb, wkb, wvb);

    qkv_mfma_kernel<<<dim3(32, 8, 3), 256, 0, stream>>>(
        xb, wqb, wkb, wvb, bq, bk, bv, qbb, kbb, vtb);

    attn_mfma32_kernel<<<dim3(256), 512, 0, stream>>>(qbb, kbb, vtb, out);
}

// Round 13
// 184.667 us; speedup vs baseline: 1.0617x; 1.0617x over previous
//
#include <hip/hip_runtime.h>
#include <hip/hip_bf16.h>
#include <stdint.h>

// Fixed problem shape: B=2, S=2048, E=1024, H=16, Dh=64, fp32 in/out.
#define S_LEN 2048
#define E_DIM 1024
#define NHEAD 16
#define DHEAD 64
#define BATCH 2

typedef short bf16x8 __attribute__((ext_vector_type(8)));  // 8 bf16 in 4 VGPRs
typedef float f32x4 __attribute__((ext_vector_type(4)));
typedef float f32x16 __attribute__((ext_vector_type(16)));

__device__ __forceinline__ ushort f2bf(float f) {
    uint32_t u = __builtin_bit_cast(uint32_t, f);
    u += 0x7fffu + ((u >> 16) & 1u);       // round-to-nearest-even
    return (ushort)(u >> 16);
}
__device__ __forceinline__ uint32_t cvtpk(float lo, float hi) {
    // single-instruction RNE pack: lo -> [15:0], hi -> [31:16]
    uint32_t r;
    asm("v_cvt_pk_bf16_f32 %0, %1, %2" : "=v"(r) : "v"(lo), "v"(hi));
    return r;
}
__device__ __forceinline__ f32x16 zero16() {
    f32x16 v;
    #pragma unroll
    for (int i = 0; i < 16; ++i) v[i] = 0.f;
    return v;
}
// async global->LDS DMA, 16B per lane; LDS dst is wave-uniform base + lane*16B
__device__ __forceinline__ void gload16(const void* g, void* l) {
    __builtin_amdgcn_global_load_lds(
        (const __attribute__((address_space(1))) uint32_t*)g,
        (__attribute__((address_space(3))) uint32_t*)l, 16, 0, 0);
}

// ---------------------------------------------------------------------------
// fp32 -> bf16 convert: blockIdx.y selects {x, Wq, Wk, Wv}
// ---------------------------------------------------------------------------
__global__ __launch_bounds__(256) void convert_kernel(
    const float* __restrict__ x, const float* __restrict__ wq,
    const float* __restrict__ wk, const float* __restrict__ wv,
    ushort* __restrict__ xb, ushort* __restrict__ wqb,
    ushort* __restrict__ wkb, ushort* __restrict__ wvb)
{
    const int a = blockIdx.y;
    const float* src = (a == 0) ? x : (a == 1) ? wq : (a == 2) ? wk : wv;
    ushort* dst      = (a == 0) ? xb : (a == 1) ? wqb : (a == 2) ? wkb : wvb;
    const int n4 = (a == 0) ? (BATCH * S_LEN * E_DIM / 4) : (E_DIM * E_DIM / 4);
    const int idx = blockIdx.x * 256 + threadIdx.x;
    if (idx < n4) {
        float4 v = reinterpret_cast<const float4*>(src)[idx];
        ushort4 o;
        o.x = f2bf(v.x); o.y = f2bf(v.y); o.z = f2bf(v.z); o.w = f2bf(v.w);
        reinterpret_cast<ushort4*>(dst)[idx] = o;
    }
}

// ---------------------------------------------------------------------------
// MFMA GEMM v3: BK=32, TWO-PHASE pipeline (T3 minimum recipe): STAGE(next
// K-tile) issued BEFORE ds_read+MFMA(cur); one __syncthreads per K-step
// (its vmcnt(0) drain doubles as the stage-complete wait). gload16 staging
// with pre-swizzled global source (slot ^= row&3) so swizzled ds_read_b128
// frag reads are ~2-way (free) instead of 8-way conflicted.
// z=0: q = x·Wq^T -> qb [B,H,S,Dh]; z=1: k -> kb; z=2: v^T = Wv·x^T -> vtb.
// ---------------------------------------------------------------------------
__global__ __launch_bounds__(256) void qkv_mfma_kernel(
    const ushort* __restrict__ xb, const ushort* __restrict__ wqb,
    const ushort* __restrict__ wkb, const ushort* __restrict__ wvb,
    const float* __restrict__ bq, const float* __restrict__ bk,
    const float* __restrict__ bv,
    ushort* __restrict__ qb, ushort* __restrict__ kb, ushort* __restrict__ vtb)
{
    const int z = blockIdx.z;
    const ushort* Ag; const ushort* Bg; const float* bias;
    int m0, n0;
    if (z == 2) { Ag = wvb; Bg = xb;                 bias = bv;
                  m0 = blockIdx.y * 128; n0 = blockIdx.x * 128; }
    else        { Ag = xb;  Bg = (z == 0) ? wqb : wkb; bias = (z == 0) ? bq : bk;
                  m0 = blockIdx.x * 128; n0 = blockIdx.y * 128; }

    __shared__ ushort As[2][128 * 32];   // double-buffered, rows of 64B
    __shared__ ushort Bs[2][128 * 32];

    const int tid  = threadIdx.x;
    const int lane = tid & 63;
    const int wid  = tid >> 6;
    const int wr   = wid >> 1, wc = wid & 1;

    f32x4 acc[4][4];
    #pragma unroll
    for (int i = 0; i < 4; ++i)
        #pragma unroll
        for (int j = 0; j < 4; ++j) acc[i][j] = (f32x4){0.f, 0.f, 0.f, 0.f};

    const int crow  = lane >> 2;        // 0..15 row within 16-row chunk
    const int cslot = lane & 3;         // 16B slot within 64B row
    const int lr    = lane & 15;
    const int lq    = lane >> 4;        // 0..3

    // stage one K-tile (BK=32) into buffer bb; source slot pre-swizzled
    auto stage = [&](int bb, int k0) {
        #pragma unroll
        for (int j = 0; j < 2; ++j) {
            const int rbase = wid * 32 + j * 16;
            const int srow  = rbase + crow;
            const int ss    = cslot ^ (srow & 3);
            gload16(&Ag[(size_t)(m0 + srow) * E_DIM + k0 + ss * 8],
                    &As[bb][rbase * 32]);
            gload16(&Bg[(size_t)(n0 + srow) * E_DIM + k0 + ss * 8],
                    &Bs[bb][rbase * 32]);
        }
    };

    stage(0, 0);
    __syncthreads();                     // tile 0 staged

    const int NT = E_DIM / 32;           // 32 K-steps
    for (int kt = 0; kt < NT; ++kt) {
        const int bb = kt & 1;
        if (kt + 1 < NT) stage(bb ^ 1, (kt + 1) * 32);   // overlap with compute

        bf16x8 af[4], bf[4];
        #pragma unroll
        for (int mi = 0; mi < 4; ++mi) {
            const int row = wr * 64 + mi * 16 + lr;
            af[mi] = *reinterpret_cast<const bf16x8*>(
                &As[bb][row * 32 + (lq ^ (row & 3)) * 8]);
        }
        #pragma unroll
        for (int ni = 0; ni < 4; ++ni) {
            const int row = wc * 64 + ni * 16 + lr;
            bf[ni] = *reinterpret_cast<const bf16x8*>(
                &Bs[bb][row * 32 + (lq ^ (row & 3)) * 8]);
        }
        #pragma unroll
        for (int mi = 0; mi < 4; ++mi)
            #pragma unroll
            for (int ni = 0; ni < 4; ++ni)
                acc[mi][ni] = __builtin_amdgcn_mfma_f32_16x16x32_bf16(
                    af[mi], bf[ni], acc[mi][ni], 0, 0, 0);

        __syncthreads();   // drains vmcnt (next tile staged) + all reads done
    }

    const int rq = lane >> 4;
    #pragma unroll
    for (int mi = 0; mi < 4; ++mi) {
        #pragma unroll
        for (int ni = 0; ni < 4; ++ni) {
            #pragma unroll
            for (int r = 0; r < 4; ++r) {
                const int i = m0 + wr * 64 + mi * 16 + rq * 4 + r;
                const int j = n0 + wc * 64 + ni * 16 + lr;
                float val = acc[mi][ni][r];
                if (z == 2) {
                    val += bias[i];
                    const int h = i >> 6, d = i & 63;
                    const int b = j >> 11, s = j & (S_LEN - 1);
                    vtb[(((size_t)(b * NHEAD + h)) * DHEAD + d) * S_LEN + s] = f2bf(val);
                } else {
                    val += bias[j];
                    const int h = j >> 6, d = j & 63;
                    const int b = i >> 11, s = i & (S_LEN - 1);
                    ushort* o = (z == 0) ? qb : kb;
                    o[(((size_t)(b * NHEAD + h)) * S_LEN + s) * DHEAD + d] = f2bf(val);
                }
            }
        }
    }
}

// ---------------------------------------------------------------------------
// Attention v5 = v4 + permlane32_swap P-redistribution (T12: one swap fills
// two PV-frag words; replaces 16 shfl + 16 selects with 8 permlane) +
// s_setprio(1) around MFMA clusters (T5).
// 8 waves x 32 q = QBLK 256; KV tiles of 64, double-buffered, T14 prefetch.
// grid = 256 blocks x 512 threads; LDS 64 KB.
// ---------------------------------------------------------------------------
__global__ __launch_bounds__(512) void attn_mfma32_kernel(
    const ushort* __restrict__ qb, const ushort* __restrict__ kb,
    const ushort* __restrict__ vtb, float* __restrict__ out)
{
    // XCD-aware bijective swizzle: 256 blocks, 8 q-blocks per (b,h) share L2
    const int bid = blockIdx.x;
    const int swzb = (bid & 7) * 32 + (bid >> 3);
    const int bh = swzb >> 3;            // 0..31
    const int q0 = (swzb & 7) * 256;
    const int b = bh >> 4, h = bh & 15;
    const ushort* Q  = qb  + (size_t)bh * S_LEN * DHEAD;
    const ushort* K  = kb  + (size_t)bh * S_LEN * DHEAD;
    const ushort* Vt = vtb + (size_t)bh * DHEAD * S_LEN;   // [Dh][S]

    __shared__ ushort Qs[256 * 64];      // 32 KB
    __shared__ ushort KV[2][2 * 64 * 64];// 2 x (Ks 8KB | Vs 8KB) = 32 KB

    const int tid  = threadIdx.x;        // 0..511
    const int lane = tid & 63;
    const int wid  = tid >> 6;           // 0..7
    const int hi   = lane >> 5;          // k-half selector in A/B frags
    const int l31  = lane & 31;
    const int swzr = (lane & 7) << 3;    // frag-read swizzle (ushort units)
    const float SC = 0.125f;             // 1/sqrt(64); ln-domain softmax

    const int stslot = (tid & 7) * 8;    // staging: 8 lanes x 16B per row
    const int strow  = tid >> 3;         // 0..63

    // ---- stage Q [256][64] swizzled ----
    #pragma unroll
    for (int p = 0; p < 4; ++p) {
        const int row = strow + p * 64;
        bf16x8 v = *reinterpret_cast<const bf16x8*>(
            &Q[(size_t)(q0 + row) * DHEAD + stslot]);
        *reinterpret_cast<bf16x8*>(
            &Qs[row * 64 + (stslot ^ ((row & 7) << 3))]) = v;
    }

    // issue tile-0 K/V loads (one 16B chunk per thread)
    bf16x8 kreg, vreg;
    kreg = *reinterpret_cast<const bf16x8*>(&K[(size_t)strow * DHEAD + stslot]);
    vreg = *reinterpret_cast<const bf16x8*>(&Vt[(size_t)strow * S_LEN + stslot]);
    __syncthreads();                     // Qs visible

    bf16x8 qf[4];
    {
        const int qrow = wid * 32 + l31;
        #pragma unroll
        for (int st = 0; st < 4; ++st)
            qf[st] = *reinterpret_cast<const bf16x8*>(
                &Qs[qrow * 64 + ((st * 16 + hi * 8) ^ ((qrow & 7) << 3))]);
    }

    // write tile 0 into buf 0
    {
        const int sw = strow * 64 + (stslot ^ ((strow & 7) << 3));
        *reinterpret_cast<bf16x8*>(&KV[0][sw])           = kreg;
        *reinterpret_cast<bf16x8*>(&KV[0][64 * 64 + sw]) = vreg;
    }
    __syncthreads();

    float m_run = -1e30f, l_run = 0.f;
    f32x16 oacc[2] = {zero16(), zero16()};
    int cur = 0;

    for (int t0 = 0; t0 < S_LEN; t0 += 64) {
        const bool more = (t0 + 64 < S_LEN);
        if (more) {                      // T14: issue next-tile loads EARLY
            const int tn = t0 + 64;
            kreg = *reinterpret_cast<const bf16x8*>(
                &K[(size_t)(tn + strow) * DHEAD + stslot]);
            vreg = *reinterpret_cast<const bf16x8*>(
                &Vt[(size_t)strow * S_LEN + tn + stslot]);
        }

        const ushort* Ks = &KV[cur][0];
        const ushort* Vs = &KV[cur][64 * 64];

        // ---- swapped QK^T: C[row=kv][col=q] ----
        f32x16 sacc[2] = {zero16(), zero16()};
        __builtin_amdgcn_s_setprio(1);
        #pragma unroll
        for (int t = 0; t < 2; ++t) {
            const int kbase = (t * 32 + l31) * 64;
            #pragma unroll
            for (int st = 0; st < 4; ++st) {
                bf16x8 kf = *reinterpret_cast<const bf16x8*>(
                    &Ks[kbase + ((st * 16 + hi * 8) ^ swzr)]);
                sacc[t] = __builtin_amdgcn_mfma_f32_32x32x16_bf16(
                    kf, qf[st], sacc[t], 0, 0, 0);
            }
        }
        __builtin_amdgcn_s_setprio(0);

        // ---- tree row-max (depth 5, q = lane&31 lane-local) ----
        float m8[8];
        #pragma unroll
        for (int i = 0; i < 8; ++i)
            m8[i] = fmaxf(fmaxf(sacc[0][i], sacc[0][i + 8]),
                          fmaxf(sacc[1][i], sacc[1][i + 8]));
        float mx = fmaxf(fmaxf(fmaxf(m8[0], m8[4]), fmaxf(m8[1], m8[5])),
                         fmaxf(fmaxf(m8[2], m8[6]), fmaxf(m8[3], m8[7])));
        mx = fmaxf(mx, __shfl_xor(mx, 32));
        const float mt = mx * SC;

        if (__any(mt > m_run + 8.0f)) {          // defer-max (T13)
            const float mn = fmaxf(m_run, mt);
            const float al = __expf(m_run - mn);
            m_run = mn;
            l_run *= al;
            #pragma unroll
            for (int r = 0; r < 16; ++r) { oacc[0][r] *= al; oacc[1][r] *= al; }
        }

        // ---- p = exp(s*SC - m); cvt_pk pairs; permlane32_swap -> P frags ----
        float csum[4];
        uint32_t w[4][4];                        // [chunk][word] PV B-frag words
        #pragma unroll
        for (int t = 0; t < 2; ++t) {
            #pragma unroll
            for (int half = 0; half < 2; ++half) {
                float p[8];
                #pragma unroll
                for (int j = 0; j < 8; ++j)
                    p[j] = __expf(fmaf(sacc[t][half * 8 + j], SC, -m_run));
                const int c = t * 2 + half;
                csum[c] = (p[0] + p[1]) + (p[2] + p[3]) +
                          ((p[4] + p[5]) + (p[6] + p[7]));
                // w0/w2 from (p0..p3 | p4..p7 swap across lane-32 boundary):
                // after swap: w0 = {a.lo-lanes, b.lo-lanes}, w2 = {a.hi, b.hi}
                uint32_t w0 = cvtpk(p[0], p[1]);
                uint32_t w1 = cvtpk(p[2], p[3]);
                uint32_t w2 = cvtpk(p[4], p[5]);
                uint32_t w3 = cvtpk(p[6], p[7]);
                asm volatile("v_permlane32_swap_b32 %0, %1"
                             : "+v"(w0), "+v"(w2));
                asm volatile("v_permlane32_swap_b32 %0, %1"
                             : "+v"(w1), "+v"(w3));
                w[c][0] = w0; w[c][1] = w1; w[c][2] = w2; w[c][3] = w3;
            }
        }
        float lsum = (csum[0] + csum[1]) + (csum[2] + csum[3]);
        lsum += __shfl_xor(lsum, 32);
        l_run += lsum;

        // ---- PV (swapped): oacc[dblk] += mfma(Vt_frag, P_frag) -> C[d][q] ----
        __builtin_amdgcn_s_setprio(1);
        #pragma unroll
        for (int c = 0; c < 4; ++c) {
            union { uint32_t u[4]; bf16x8 v; } pf;
            pf.u[0] = w[c][0]; pf.u[1] = w[c][1];
            pf.u[2] = w[c][2]; pf.u[3] = w[c][3];
            #pragma unroll
            for (int dblk = 0; dblk < 2; ++dblk) {
                const int vrow = dblk * 32 + l31;
                bf16x8 vf = *reinterpret_cast<const bf16x8*>(
                    &Vs[vrow * 64 + ((c * 16 + hi * 8) ^ swzr)]);
                oacc[dblk] = __builtin_amdgcn_mfma_f32_32x32x16_bf16(
                    vf, pf.v, oacc[dblk], 0, 0, 0);
            }
        }
        __builtin_amdgcn_s_setprio(0);

        if (more) {
            __syncthreads();             // all waves done compute(t)
            const int sw = strow * 64 + (stslot ^ ((strow & 7) << 3));
            *reinterpret_cast<bf16x8*>(&KV[cur ^ 1][sw])           = kreg;
            *reinterpret_cast<bf16x8*>(&KV[cur ^ 1][64 * 64 + sw]) = vreg;
            __syncthreads();             // writes visible
            cur ^= 1;
        }
    }

    // ---- epilogue: out[b][q][h*64+d], d = (r&3)+8*(r>>2)+4*hi+32*dblk ----
    const float inv = 1.f / l_run;
    const int qg = q0 + wid * 32 + l31;
    float* obase = &out[((size_t)(b * S_LEN + qg)) * E_DIM + h * DHEAD];
    #pragma unroll
    for (int dblk = 0; dblk < 2; ++dblk) {
        #pragma unroll
        for (int g = 0; g < 4; ++g) {
            float4 f;
            f.x = oacc[dblk][g * 4 + 0] * inv;
            f.y = oacc[dblk][g * 4 + 1] * inv;
            f.z = oacc[dblk][g * 4 + 2] * inv;
            f.w = oacc[dblk][g * 4 + 3] * inv;
            *reinterpret_cast<float4*>(&obase[dblk * 32 + g * 8 + hi * 4]) = f;
        }
    }
}

// ---------------------------------------------------------------------------
extern "C" void kernel_launch(void* const* d_in, const int* in_sizes, int n_in,
                              void* d_out, int out_size, void* d_ws, size_t ws_size,
                              hipStream_t stream) {
    const float* x  = (const float*)d_in[0];
    const float* Wq = (const float*)d_in[1];
    const float* bq = (const float*)d_in[2];
    const float* Wk = (const float*)d_in[3];
    const float* bk = (const float*)d_in[4];
    const float* Wv = (const float*)d_in[5];
    const float* bv = (const float*)d_in[6];
    float* out = (float*)d_out;

    const size_t XN = (size_t)BATCH * S_LEN * E_DIM;   // 4M elems
    const size_t WN = (size_t)E_DIM * E_DIM;           // 1M elems
    ushort* xb  = (ushort*)d_ws;
    ushort* wqb = xb  + XN;
    ushort* wkb = wqb + WN;
    ushort* wvb = wkb + WN;
    ushort* qbb = wvb + WN;
    ushort* kbb = qbb + XN;
    ushort* vtb = kbb + XN;   // total ~38 MB

    convert_kernel<<<dim3(4096, 4), 256, 0, stream>>>(
        x, Wq, Wk, Wv, xb, wqb, wkb, wvb);

    qkv_mfma_kernel<<<dim3(32, 8, 3), 256, 0, stream>>>(
        xb, wqb, wkb, wvb, bq, bk, bv, qbb, kbb, vtb);

    attn_mfma32_kernel<<<dim3(256), 512, 0, stream>>>(qbb, kbb, vtb, out);
}